// Round 1
// baseline (9013.306 us; speedup 1.0000x reference)
//
#include <hip/hip_runtime.h>
#include <hip/hip_bf16.h>

// LSTM: B=64, T=512, V=32000, E=256, H=512, O=1
// Persistent kernel, weight-stationary in VGPRs, 8 independent barrier
// domains of 32 blocks each (one batch-group of 8 sequences per domain).
#define TB 512
#define NB 64
#define EE 256
#define HH 512
#define NBG 8        // batch groups (= barrier domains), bg = blockIdx & 7 (XCD-aligned)
#define NUG 32       // unit groups per batch group
#define MB 8         // batches per block
#define MU 16        // hidden units per block (x4 gates = 64 cols)
#define NCOL (4*MU)
#define NTHREADS 128 // 2 waves; each wave owns 32 gate-columns

typedef __bf16 bf16_t;
typedef bf16_t bf16x8 __attribute__((ext_vector_type(8)));
typedef float  f32x4  __attribute__((ext_vector_type(4)));

__device__ __forceinline__ float sigf(float x) { return 1.0f / (1.0f + __expf(-x)); }
__device__ __forceinline__ float tanhfast(float x) {
    float xc = fminf(fmaxf(x, -15.0f), 15.0f);
    float e  = __expf(2.0f * xc);
    return (e - 1.0f) / (e + 1.0f);
}

__global__ __launch_bounds__(NTHREADS, 1)
void lstm_persistent(const int* __restrict__ words,
                     const float* __restrict__ emb,
                     const float* __restrict__ Wi,
                     const float* __restrict__ bi,
                     const float* __restrict__ Wh,
                     const float* __restrict__ bh,
                     const float* __restrict__ Wfc,
                     const float* __restrict__ bfc,
                     float* __restrict__ out,          // [64] out  +  [64*512] h
                     unsigned int* __restrict__ ctr,   // 8 counters, 256B apart
                     bf16_t* __restrict__ hbuf)        // [2][64][512] bf16
{
    const int tid  = threadIdx.x;
    const int lane = tid & 63;
    const int wv   = tid >> 6;            // wave 0..1
    const int bg   = blockIdx.x & 7;      // batch group -> same XCD for whole group
    const int ug   = blockIdx.x >> 3;     // unit group 0..31

    __shared__ __align__(16) bf16_t h_lds[16][HH];
    __shared__ __align__(16) bf16_t x_lds[16][EE];
    __shared__ __align__(16) float  P_lds[16][NCOL];

    // zero LDS once (rows 8..15 of h/x stay zero forever -> clean MFMA A rows)
    for (int i = tid; i < 16*HH; i += NTHREADS) ((bf16_t*)h_lds)[i] = (bf16_t)0.0f;
    for (int i = tid; i < 16*EE; i += NTHREADS) ((bf16_t*)x_lds)[i] = (bf16_t)0.0f;

    const int kgrp = lane >> 4;           // 0..3 (k-octet selector)
    const int cl   = lane & 15;           // A row / B col within tile

    // ---- load weight fragments into registers (stationary across all 512 steps) ----
    // col ordering within block: col = u_local*4 + gate  (so one thread later owns
    // all 4 gates of one unit contiguously in P_lds)
    bf16x8 whf[16][2];                    // [k-iter][n-tile]
    bf16x8 wif[8][2];
    float  biasn[2];
    #pragma unroll
    for (int nt = 0; nt < 2; ++nt) {
        int col = wv*32 + nt*16 + cl;     // 0..63
        int ul  = col >> 2, g = col & 3;
        int row = g*HH + ug*MU + ul;      // row into [4*H, *] weight matrices
        const float* wr = Wh + (size_t)row*HH;
        #pragma unroll
        for (int kt = 0; kt < 16; ++kt) {
            int k0 = kt*32 + kgrp*8;
            bf16x8 v;
            #pragma unroll
            for (int j = 0; j < 8; ++j) v[j] = (bf16_t)wr[k0 + j];
            whf[kt][nt] = v;
        }
        const float* wir = Wi + (size_t)row*EE;
        #pragma unroll
        for (int kt = 0; kt < 8; ++kt) {
            int k0 = kt*32 + kgrp*8;
            bf16x8 v;
            #pragma unroll
            for (int j = 0; j < 8; ++j) v[j] = (bf16_t)wir[k0 + j];
            wif[kt][nt] = v;
        }
        biasn[nt] = bi[row] + bh[row];
    }

    // cell state: thread owns (batch ab, unit au)
    const int ab = tid >> 4;              // 0..7
    const int au = tid & 15;              // 0..15
    float cst = 0.0f;

    unsigned int* myctr = ctr + bg*64;    // 256B apart per group

    __syncthreads();

    for (int t = 0; t < TB; ++t) {
        // ---- stage x_t = emb[words[:, t]]  (does not depend on h) ----
        {
            int b = tid >> 4, ch = tid & 15;
            int word = words[(bg*MB + b)*TB + t];
            const float4* xr = (const float4*)(emb + (size_t)word*EE + ch*16);
            float4 f0 = xr[0], f1 = xr[1], f2 = xr[2], f3 = xr[3];
            bf16x8 v0, v1;
            v0[0]=(bf16_t)f0.x; v0[1]=(bf16_t)f0.y; v0[2]=(bf16_t)f0.z; v0[3]=(bf16_t)f0.w;
            v0[4]=(bf16_t)f1.x; v0[5]=(bf16_t)f1.y; v0[6]=(bf16_t)f1.z; v0[7]=(bf16_t)f1.w;
            v1[0]=(bf16_t)f2.x; v1[1]=(bf16_t)f2.y; v1[2]=(bf16_t)f2.z; v1[3]=(bf16_t)f2.w;
            v1[4]=(bf16_t)f3.x; v1[5]=(bf16_t)f3.y; v1[6]=(bf16_t)f3.z; v1[7]=(bf16_t)f3.w;
            *(bf16x8*)&x_lds[b][ch*16]     = v0;
            *(bf16x8*)&x_lds[b][ch*16 + 8] = v1;
        }
        __syncthreads();

        // ---- input-projection MFMAs first (hides part of the barrier wait) ----
        f32x4 acc0 = { biasn[0], biasn[0], biasn[0], biasn[0] };
        f32x4 acc1 = { biasn[1], biasn[1], biasn[1], biasn[1] };
        #pragma unroll
        for (int kt = 0; kt < 8; ++kt) {
            bf16x8 a = *(const bf16x8*)&x_lds[cl][kt*32 + kgrp*8];
            acc0 = __builtin_amdgcn_mfma_f32_16x16x32_bf16(a, wif[kt][0], acc0, 0, 0, 0);
            acc1 = __builtin_amdgcn_mfma_f32_16x16x32_bf16(a, wif[kt][1], acc1, 0, 0, 0);
        }

        // ---- wait for all 32 blocks of this batch group to publish h_{t-1} ----
        if (tid == 0) {
            unsigned int target = (unsigned int)(NUG * t);
            while (__hip_atomic_load(myctr, __ATOMIC_RELAXED, __HIP_MEMORY_SCOPE_AGENT) < target)
                __builtin_amdgcn_s_sleep(2);
        }
        __syncthreads();
        __threadfence();   // acquire: invalidate caches before reading peers' h

        // ---- stage h_{t-1} (bf16, 8 rows x 512) ----
        {
            const bf16_t* hsrc = hbuf + ((size_t)((t & 1) ^ 1))*NB*HH + (size_t)(bg*MB)*HH;
            int b = tid >> 4, ch = tid & 15;
            const f32x4* src = (const f32x4*)(hsrc + (size_t)b*HH) + ch*4;
            f32x4* dst = (f32x4*)(&h_lds[b][0]) + ch*4;
            #pragma unroll
            for (int j = 0; j < 4; ++j) dst[j] = src[j];
        }
        __syncthreads();

        // ---- recurrent MFMAs ----
        #pragma unroll
        for (int kt = 0; kt < 16; ++kt) {
            bf16x8 a = *(const bf16x8*)&h_lds[cl][kt*32 + kgrp*8];
            acc0 = __builtin_amdgcn_mfma_f32_16x16x32_bf16(a, whf[kt][0], acc0, 0, 0, 0);
            acc1 = __builtin_amdgcn_mfma_f32_16x16x32_bf16(a, whf[kt][1], acc1, 0, 0, 0);
        }

        // ---- write preactivations: D row=(lane>>4)*4+reg, col=lane&15 ----
        #pragma unroll
        for (int r = 0; r < 4; ++r) {
            P_lds[kgrp*4 + r][wv*32 + cl]      = acc0[r];
            P_lds[kgrp*4 + r][wv*32 + 16 + cl] = acc1[r];
        }
        __syncthreads();

        // ---- activations + cell update (thread owns (ab, au)) ----
        {
            float4 p = *(const float4*)&P_lds[ab][au*4];   // gates r,f,g,o
            float rg = sigf(p.x), fg = sigf(p.y);
            float gg = tanhfast(p.z), og = sigf(p.w);
            cst = fg * cst + rg * gg;
            float hval = og * tanhfast(cst);
            hbuf[((size_t)(t & 1))*NB*HH + (size_t)(bg*MB + ab)*HH + ug*MU + au] = (bf16_t)hval;
            if (t == TB - 1)
                out[64 + (size_t)(bg*MB + ab)*HH + ug*MU + au] = hval;
        }

        // ---- publish h_t ----
        __threadfence();
        __syncthreads();
        if (tid == 0)
            __hip_atomic_fetch_add(myctr, 1u, __ATOMIC_RELAXED, __HIP_MEMORY_SCOPE_AGENT);
    }

    // ---- final FC head: one block per batch group ----
    if (ug == 0) {
        if (tid == 0) {
            while (__hip_atomic_load(myctr, __ATOMIC_RELAXED, __HIP_MEMORY_SCOPE_AGENT)
                   < (unsigned int)(NUG * TB))
                __builtin_amdgcn_s_sleep(2);
        }
        __syncthreads();
        __threadfence();
        if (tid < 64) {
            int b = tid >> 3, seg = tid & 7;
            const bf16_t* hrow = hbuf + ((size_t)((TB-1) & 1))*NB*HH + (size_t)(bg*MB + b)*HH;
            float s = 0.0f;
            for (int k = seg*64; k < seg*64 + 64; ++k)
                s += (float)hrow[k] * Wfc[k];
            #pragma unroll
            for (int d = 4; d >= 1; d >>= 1)
                s += __shfl_down(s, d, 8);
            if (seg == 0)
                out[bg*MB + b] = sigf(s + bfc[0]);
        }
    }
}

extern "C" void kernel_launch(void* const* d_in, const int* in_sizes, int n_in,
                              void* d_out, int out_size, void* d_ws, size_t ws_size,
                              hipStream_t stream) {
    (void)in_sizes; (void)n_in; (void)out_size; (void)ws_size;
    const int*   words = (const int*)d_in[0];
    const float* emb   = (const float*)d_in[1];
    const float* Wi    = (const float*)d_in[2];
    const float* bi    = (const float*)d_in[3];
    const float* Wh    = (const float*)d_in[4];
    const float* bh    = (const float*)d_in[5];
    const float* Wfc   = (const float*)d_in[6];
    const float* bfc   = (const float*)d_in[7];
    float* out = (float*)d_out;

    unsigned int* ctr = (unsigned int*)d_ws;
    bf16_t* hbuf = (bf16_t*)((char*)d_ws + 4096);

    // zero barrier counters + h double-buffer (h_{-1} = 0) every launch
    hipMemsetAsync(d_ws, 0, 4096 + (size_t)2*NB*HH*sizeof(bf16_t), stream);

    lstm_persistent<<<dim3(NBG*NUG), dim3(NTHREADS), 0, stream>>>(
        words, emb, Wi, bi, Wh, bh, Wfc, bfc, out, ctr, hbuf);
}

// Round 4
// 2422.598 us; speedup vs baseline: 3.7205x; 3.7205x over previous
//
#include <hip/hip_runtime.h>
#include <hip/hip_bf16.h>

// LSTM: B=64, T=512, V=32000, E=256, H=512, O=1
// Persistent kernel. 4 sync domains (batch groups of 16), 16 blocks each,
// 256 threads (4 waves). Cross-block exchange: sc1 atomics for data,
// per-block flags (no RMW), compiler-verified acquire/release agent fences.
#define TB 512
#define NB 64
#define EE 256
#define HH 512
#define NG 4          // batch groups (sync domains)
#define GB 16         // batches per group (= full MFMA A-tile rows)
#define NBLK 16       // blocks per group
#define NT 256        // threads per block (4 waves)
#define NCOLP 132     // P_lds padded row (128 cols + 4)

typedef __bf16 bf16_t;
typedef bf16_t bf16x8 __attribute__((ext_vector_type(8)));
typedef float  f32x4  __attribute__((ext_vector_type(4)));
typedef unsigned long long u64;

__device__ __forceinline__ float sigf(float x) { return 1.0f / (1.0f + __expf(-x)); }
__device__ __forceinline__ float tanhfast(float x) {
    float xc = fminf(fmaxf(x, -15.0f), 15.0f);
    float e  = __expf(2.0f * xc);
    return (e - 1.0f) / (e + 1.0f);
}
__device__ __forceinline__ unsigned bfbits(float f) {
    bf16_t h = (bf16_t)f;
    return (unsigned)__builtin_bit_cast(unsigned short, h);
}
__device__ __forceinline__ bf16x8 cvt8(float4 a, float4 b) {
    bf16x8 v;
    v[0]=(bf16_t)a.x; v[1]=(bf16_t)a.y; v[2]=(bf16_t)a.z; v[3]=(bf16_t)a.w;
    v[4]=(bf16_t)b.x; v[5]=(bf16_t)b.y; v[6]=(bf16_t)b.z; v[7]=(bf16_t)b.w;
    return v;
}

__global__ __launch_bounds__(NT, 1)
void lstm_persistent(const int* __restrict__ words,
                     const float* __restrict__ emb,
                     const float* __restrict__ Wi,
                     const float* __restrict__ bi,
                     const float* __restrict__ Wh,
                     const float* __restrict__ bh,
                     const float* __restrict__ Wfc,
                     const float* __restrict__ bfc,
                     float* __restrict__ out,        // [64] head + [64*512] h (fp32)
                     unsigned* __restrict__ flags,   // NG groups, 256B apart, NBLK uints each
                     bf16_t* __restrict__ hbuf)      // [2][64][512] bf16
{
    const int tid  = threadIdx.x;
    const int lane = tid & 63;
    const int wv   = tid >> 6;        // 0..3
    const int bg   = blockIdx.x & 3;  // batch group / sync domain
    const int ug   = blockIdx.x >> 2; // unit group 0..15
    const int kgrp = lane >> 4;       // k-octet selector 0..3
    const int cl   = lane & 15;       // A row / B col within 16x16 tile

    __shared__ __align__(16) bf16_t h_lds[16][HH];       // 16 KiB
    __shared__ __align__(16) bf16_t x_lds[2][16][EE];    // 16 KiB (double buffer)
    __shared__ __align__(16) float  P_lds[16][NCOLP];    // 8.25 KiB

    // zero h_lds (h_{-1} = 0)
    for (int i = tid; i < 16*HH/2; i += NT) ((unsigned*)h_lds)[i] = 0u;

    // ---- weight fragments, stationary in registers for all 512 steps ----
    // col = u_local*4 + gate ; row into [4H, *] = gate*H + ug*32 + u_local
    bf16x8 whf[16][2];
    bf16x8 wif[8][2];
    float  biasn[2];
    #pragma unroll
    for (int nt = 0; nt < 2; ++nt) {
        int col = wv*32 + nt*16 + cl;         // 0..127
        int ul  = col >> 2, g = col & 3;
        int row = g*HH + ug*32 + ul;
        const float* wr = Wh + (size_t)row*HH;
        #pragma unroll
        for (int kt = 0; kt < 16; ++kt) {
            const float4* p = (const float4*)(wr + kt*32 + kgrp*8);
            whf[kt][nt] = cvt8(p[0], p[1]);
        }
        const float* wir = Wi + (size_t)row*EE;
        #pragma unroll
        for (int kt = 0; kt < 8; ++kt) {
            const float4* p = (const float4*)(wir + kt*32 + kgrp*8);
            wif[kt][nt] = cvt8(p[0], p[1]);
        }
        biasn[nt] = bi[row] + bh[row];
    }

    // staging coords: row sb (0..15), chunk sc (0..15)
    const int sb = tid & 15, sc = tid >> 4;
    const int swz = (sb & 7) << 3;            // XOR swizzle key (units of 8 elems)

    // prologue: stage x(0)
    {
        int word = words[(bg*GB + sb)*TB + 0];
        const float4* p = (const float4*)(emb + (size_t)word*EE + sc*16);
        float4 a=p[0], b=p[1], c=p[2], d=p[3];
        *(bf16x8*)&x_lds[0][sb][(sc*16    ) ^ swz] = cvt8(a, b);
        *(bf16x8*)&x_lds[0][sb][(sc*16 + 8) ^ swz] = cvt8(c, d);
    }

    unsigned* gflag = flags + bg*64;          // 256B apart per group
    float c0 = 0.f, c1 = 0.f;
    __syncthreads();

    for (int t = 0; t < TB; ++t) {
        // ---- input-projection MFMAs (independent of h) ----
        f32x4 acc0 = { biasn[0], biasn[0], biasn[0], biasn[0] };
        f32x4 acc1 = { biasn[1], biasn[1], biasn[1], biasn[1] };
        const bf16_t (*xl)[EE] = x_lds[t & 1];
        #pragma unroll
        for (int kt = 0; kt < 8; ++kt) {
            bf16x8 a = *(const bf16x8*)&xl[cl][(kt*32 + kgrp*8) ^ ((cl & 7) << 3)];
            acc0 = __builtin_amdgcn_mfma_f32_16x16x32_bf16(a, wif[kt][0], acc0, 0, 0, 0);
            acc1 = __builtin_amdgcn_mfma_f32_16x16x32_bf16(a, wif[kt][1], acc1, 0, 0, 0);
        }

        // ---- issue x(t+1) prefetch BEFORE the poll (emb is read-only; the
        //      acquire fence's vmcnt wait then overlaps poll latency) ----
        float4 xa, xb, xc, xd;
        const bool havex = (t + 1 < TB);
        if (havex) {
            int word = words[(bg*GB + sb)*TB + (t + 1)];
            const float4* p = (const float4*)(emb + (size_t)word*EE + sc*16);
            xa = p[0]; xb = p[1]; xc = p[2]; xd = p[3];
        }

        // ---- wait for all 16 blocks of this group to publish h_{t-1} ----
        if (t > 0) {
            if (wv == 0) {
                unsigned tgt = (unsigned)t;
                for (;;) {
                    unsigned v = (lane < NBLK)
                        ? __hip_atomic_load(&gflag[lane], __ATOMIC_RELAXED, __HIP_MEMORY_SCOPE_AGENT)
                        : tgt;
                    if (__all((int)(v >= tgt))) break;
                    __builtin_amdgcn_s_sleep(1);
                }
                // acquire: waitcnt + buffer_inv — stale L1/L2 lines die here
                __builtin_amdgcn_fence(__ATOMIC_ACQUIRE, "agent");
            }
            __syncthreads();
        }

        // ---- h_{t-1} loads: full 32 elements = 8x u64 (R2/R3 bug: only 4) ----
        if (t > 0) {
            const u64* src = (const u64*)(hbuf + (((size_t)((t & 1) ^ 1))*NB + bg*GB + sb)*HH + sc*32);
            u64 hr[8];
            #pragma unroll
            for (int q = 0; q < 8; ++q)
                hr[q] = __hip_atomic_load(src + q, __ATOMIC_RELAXED, __HIP_MEMORY_SCOPE_AGENT);
            // octet q (8 elems = 16B) -> physical octet (4*sc + q) ^ (sb&7)
            #pragma unroll
            for (int q = 0; q < 4; ++q) {
                int phys = (sc*32 + q*8) ^ swz;
                *(u64*)&h_lds[sb][phys]     = hr[2*q];
                *(u64*)&h_lds[sb][phys + 4] = hr[2*q + 1];
            }
            __syncthreads();
        }

        // ---- recurrent MFMAs ----
        #pragma unroll
        for (int kt = 0; kt < 16; ++kt) {
            bf16x8 a = *(const bf16x8*)&h_lds[cl][(kt*32 + kgrp*8) ^ ((cl & 7) << 3)];
            acc0 = __builtin_amdgcn_mfma_f32_16x16x32_bf16(a, whf[kt][0], acc0, 0, 0, 0);
            acc1 = __builtin_amdgcn_mfma_f32_16x16x32_bf16(a, whf[kt][1], acc1, 0, 0, 0);
        }

        // ---- stash x(t+1) into the other x buffer ----
        if (havex) {
            bf16_t (*xn)[EE] = x_lds[(t + 1) & 1];
            *(bf16x8*)&xn[sb][(sc*16    ) ^ swz] = cvt8(xa, xb);
            *(bf16x8*)&xn[sb][(sc*16 + 8) ^ swz] = cvt8(xc, xd);
        }

        // ---- preactivations to LDS: D row=(kgrp*4+r)=batch, col=cl ----
        #pragma unroll
        for (int r = 0; r < 4; ++r) {
            P_lds[kgrp*4 + r][wv*32 + cl]      = acc0[r];
            P_lds[kgrp*4 + r][wv*32 + 16 + cl] = acc1[r];
        }
        __syncthreads();

        // ---- activations + cell update: thread owns (b,u) and (b+8,u) ----
        {
            int b = tid >> 5, u = tid & 31;
            float4 g0 = *(const float4*)&P_lds[b][u*4];
            float4 g1 = *(const float4*)&P_lds[b + 8][u*4];
            float r0 = sigf(g0.x), f0 = sigf(g0.y), z0 = tanhfast(g0.z), o0 = sigf(g0.w);
            float r1 = sigf(g1.x), f1 = sigf(g1.y), z1 = tanhfast(g1.z), o1 = sigf(g1.w);
            c0 = f0*c0 + r0*z0;
            c1 = f1*c1 + r1*z1;
            float h0 = o0*tanhfast(c0);
            float h1 = o1*tanhfast(c1);
            if (t == TB - 1) {
                out[64 + (size_t)(bg*GB + b    )*HH + ug*32 + u] = h0;
                out[64 + (size_t)(bg*GB + b + 8)*HH + ug*32 + u] = h1;
            }
            // pack 2 bf16 per dword, publish via sc1 stores
            unsigned s0 = bfbits(h0), s1 = bfbits(h1);
            unsigned n0 = (unsigned)__shfl_down((int)s0, 1);
            unsigned n1 = (unsigned)__shfl_down((int)s1, 1);
            if (!(u & 1)) {
                size_t e0 = ((size_t)(t & 1)*NB + bg*GB + b    )*HH + ug*32 + u;
                size_t e1 = ((size_t)(t & 1)*NB + bg*GB + b + 8)*HH + ug*32 + u;
                __hip_atomic_store((unsigned*)(hbuf + e0), (s0 & 0xFFFFu) | (n0 << 16),
                                   __ATOMIC_RELAXED, __HIP_MEMORY_SCOPE_AGENT);
                __hip_atomic_store((unsigned*)(hbuf + e1), (s1 & 0xFFFFu) | (n1 << 16),
                                   __ATOMIC_RELAXED, __HIP_MEMORY_SCOPE_AGENT);
            }
        }

        // ---- drain all threads' stores (barrier includes vmcnt(0)), then
        //      release-fence + raise our flag ----
        __syncthreads();
        if (tid == 0) {
            __builtin_amdgcn_fence(__ATOMIC_RELEASE, "agent");
            __hip_atomic_store(&gflag[ug], (unsigned)(t + 1),
                               __ATOMIC_RELAXED, __HIP_MEMORY_SCOPE_AGENT);
        }
    }

    // ---- final FC head: block ug==0 of each group ----
    if (ug == 0) {
        if (wv == 0) {
            for (;;) {
                unsigned v = (lane < NBLK)
                    ? __hip_atomic_load(&gflag[lane], __ATOMIC_RELAXED, __HIP_MEMORY_SCOPE_AGENT)
                    : (unsigned)TB;
                if (__all((int)(v >= (unsigned)TB))) break;
                __builtin_amdgcn_s_sleep(1);
            }
            __builtin_amdgcn_fence(__ATOMIC_ACQUIRE, "agent");
        }
        __syncthreads();
        {
            int b = tid >> 4, seg = tid & 15;
            const u64* hp = (const u64*)(hbuf + ((size_t)1*NB + bg*GB + b)*HH + seg*32);
            float s = 0.f;
            #pragma unroll
            for (int q = 0; q < 8; ++q) {
                u64 w = __hip_atomic_load(hp + q, __ATOMIC_RELAXED, __HIP_MEMORY_SCOPE_AGENT);
                #pragma unroll
                for (int j = 0; j < 4; ++j) {
                    float hv = __uint_as_float((unsigned)((w >> (16*j)) & 0xFFFFu) << 16);
                    s += hv * Wfc[seg*32 + q*4 + j];
                }
            }
            #pragma unroll
            for (int d = 8; d >= 1; d >>= 1) s += __shfl_down(s, d, 16);
            if (seg == 0) out[bg*GB + b] = sigf(s + bfc[0]);
        }
    }
}

extern "C" void kernel_launch(void* const* d_in, const int* in_sizes, int n_in,
                              void* d_out, int out_size, void* d_ws, size_t ws_size,
                              hipStream_t stream) {
    (void)in_sizes; (void)n_in; (void)out_size; (void)ws_size;
    const int*   words = (const int*)d_in[0];
    const float* emb   = (const float*)d_in[1];
    const float* Wi    = (const float*)d_in[2];
    const float* bi    = (const float*)d_in[3];
    const float* Wh    = (const float*)d_in[4];
    const float* bh    = (const float*)d_in[5];
    const float* Wfc   = (const float*)d_in[6];
    const float* bfc   = (const float*)d_in[7];
    float* out = (float*)d_out;

    unsigned* flags = (unsigned*)d_ws;
    bf16_t*   hbuf  = (bf16_t*)((char*)d_ws + 4096);

    // zero flags + h double-buffer (h_{-1}=0) every launch (graph-capture safe)
    hipMemsetAsync(d_ws, 0, 4096 + (size_t)2*NB*HH*sizeof(bf16_t), stream);

    lstm_persistent<<<dim3(NG*NBLK), dim3(NT), 0, stream>>>(
        words, emb, Wi, bi, Wh, bh, Wfc, bfc, out, flags, hbuf);
}

// Round 5
// 2230.407 us; speedup vs baseline: 4.0411x; 1.0862x over previous
//
#include <hip/hip_runtime.h>
#include <hip/hip_bf16.h>

// LSTM: B=64, T=512, V=32000, E=256, H=512, O=1
// Persistent kernel. 4 sync domains (batch groups of 16), 16 blocks each,
// 256 threads (4 waves). Cross-block h exchange via TAGGED 8-byte atomics:
// each u64 = (tag << 32) | (bf16 h[2k+1] << 16) | bf16 h[2k].  The tag
// travels with the data, so there are NO flags, NO fences, NO vmcnt drains,
// and no end-of-step barrier.  2-slot double buffer gives WAR safety.
#define TB 512
#define NB 64
#define EE 256
#define HH 512
#define NG 4          // batch groups (sync domains)
#define GB 16         // batches per group (= full MFMA A-tile rows)
#define NT 256        // threads per block (4 waves)
#define NCOLP 132     // P_lds padded row (128 cols + 4)
#define NPAIR (HH/2)  // 256 tagged pairs per batch row

typedef __bf16 bf16_t;
typedef bf16_t bf16x8 __attribute__((ext_vector_type(8)));
typedef float  f32x4  __attribute__((ext_vector_type(4)));
typedef unsigned long long u64;
typedef unsigned u32;

__device__ __forceinline__ float sigf(float x) { return 1.0f / (1.0f + __expf(-x)); }
__device__ __forceinline__ float tanhfast(float x) {
    float xc = fminf(fmaxf(x, -15.0f), 15.0f);
    float e  = __expf(2.0f * xc);
    return (e - 1.0f) / (e + 1.0f);
}
__device__ __forceinline__ unsigned bfbits(float f) {
    bf16_t h = (bf16_t)f;
    return (unsigned)__builtin_bit_cast(unsigned short, h);
}
__device__ __forceinline__ bf16x8 cvt8(float4 a, float4 b) {
    bf16x8 v;
    v[0]=(bf16_t)a.x; v[1]=(bf16_t)a.y; v[2]=(bf16_t)a.z; v[3]=(bf16_t)a.w;
    v[4]=(bf16_t)b.x; v[5]=(bf16_t)b.y; v[6]=(bf16_t)b.z; v[7]=(bf16_t)b.w;
    return v;
}

__global__ __launch_bounds__(NT, 1)
void lstm_persistent(const int* __restrict__ words,
                     const float* __restrict__ emb,
                     const float* __restrict__ Wi,
                     const float* __restrict__ bi,
                     const float* __restrict__ Wh,
                     const float* __restrict__ bh,
                     const float* __restrict__ Wfc,
                     const float* __restrict__ bfc,
                     float* __restrict__ out,        // [64] head + [64*512] h (fp32)
                     u64* __restrict__ tagH)         // [2][NB][NPAIR] tagged pairs
{
    const int tid  = threadIdx.x;
    const int lane = tid & 63;
    const int wv   = tid >> 6;        // 0..3
    const int bg   = blockIdx.x & 3;  // batch group / sync domain
    const int ug   = blockIdx.x >> 2; // unit group 0..15
    const int kgrp = lane >> 4;       // k-octet selector 0..3
    const int cl   = lane & 15;       // A row / B col within 16x16 tile

    __shared__ __align__(16) bf16_t h_lds[16][HH];       // 16 KiB
    __shared__ __align__(16) bf16_t x_lds[2][16][EE];    // 16 KiB (double buffer)
    __shared__ __align__(16) float  P_lds[16][NCOLP];    // 8.25 KiB

    // zero h_lds (h_{-1} = 0)
    for (int i = tid; i < 16*HH/2; i += NT) ((unsigned*)h_lds)[i] = 0u;

    // ---- weight fragments, stationary in registers for all 512 steps ----
    // col = u_local*4 + gate ; row into [4H, *] = gate*H + ug*32 + u_local
    bf16x8 whf[16][2];
    bf16x8 wif[8][2];
    float  biasn[2];
    #pragma unroll
    for (int nt = 0; nt < 2; ++nt) {
        int col = wv*32 + nt*16 + cl;         // 0..127
        int ul  = col >> 2, g = col & 3;
        int row = g*HH + ug*32 + ul;
        const float* wr = Wh + (size_t)row*HH;
        #pragma unroll
        for (int kt = 0; kt < 16; ++kt) {
            const float4* p = (const float4*)(wr + kt*32 + kgrp*8);
            whf[kt][nt] = cvt8(p[0], p[1]);
        }
        const float* wir = Wi + (size_t)row*EE;
        #pragma unroll
        for (int kt = 0; kt < 8; ++kt) {
            const float4* p = (const float4*)(wir + kt*32 + kgrp*8);
            wif[kt][nt] = cvt8(p[0], p[1]);
        }
        biasn[nt] = bi[row] + bh[row];
    }

    // staging coords: row sb (0..15), chunk sc (0..15)
    const int sb = tid & 15, sc = tid >> 4;
    const int swz = (sb & 7) << 3;            // XOR swizzle key (units of 8 elems)

    // prologue: stage x(0)
    {
        int word = words[(bg*GB + sb)*TB + 0];
        const float4* p = (const float4*)(emb + (size_t)word*EE + sc*16);
        float4 a=p[0], b=p[1], c=p[2], d=p[3];
        *(bf16x8*)&x_lds[0][sb][(sc*16    ) ^ swz] = cvt8(a, b);
        *(bf16x8*)&x_lds[0][sb][(sc*16 + 8) ^ swz] = cvt8(c, d);
    }

    float c0 = 0.f, c1 = 0.f;
    __syncthreads();

    for (int t = 0; t < TB; ++t) {
        // ---- input-projection MFMAs (independent of h) ----
        f32x4 acc0 = { biasn[0], biasn[0], biasn[0], biasn[0] };
        f32x4 acc1 = { biasn[1], biasn[1], biasn[1], biasn[1] };
        const bf16_t (*xl)[EE] = x_lds[t & 1];
        #pragma unroll
        for (int kt = 0; kt < 8; ++kt) {
            bf16x8 a = *(const bf16x8*)&xl[cl][(kt*32 + kgrp*8) ^ ((cl & 7) << 3)];
            acc0 = __builtin_amdgcn_mfma_f32_16x16x32_bf16(a, wif[kt][0], acc0, 0, 0, 0);
            acc1 = __builtin_amdgcn_mfma_f32_16x16x32_bf16(a, wif[kt][1], acc1, 0, 0, 0);
        }

        // ---- issue x(t+1) prefetch (latency hides under poll) ----
        float4 xa, xb, xc, xd;
        const bool havex = (t + 1 < TB);
        if (havex) {
            int word = words[(bg*GB + sb)*TB + (t + 1)];
            const float4* p = (const float4*)(emb + (size_t)word*EE + sc*16);
            xa = p[0]; xb = p[1]; xc = p[2]; xd = p[3];
        }

        // ---- poll tagged h_{t-1}: thread (sb,sc) owns pairs [sb][sc*16..+15] ----
        if (t > 0) {
            const u64* src = tagH + ((size_t)((t & 1) ^ 1))*NB*NPAIR
                                  + (size_t)(bg*GB + sb)*NPAIR + sc*16;
            const u32 tag = (u32)t;
            u64 hv[16];
            for (;;) {
                #pragma unroll
                for (int j = 0; j < 16; ++j)
                    hv[j] = __hip_atomic_load(src + j, __ATOMIC_RELAXED, __HIP_MEMORY_SCOPE_AGENT);
                bool ok = true;
                #pragma unroll
                for (int j = 0; j < 16; ++j) ok &= ((u32)(hv[j] >> 32) == tag);
                if (ok) break;
                __builtin_amdgcn_s_sleep(1);
            }
            // payload pairs -> LDS (swizzled octets, pack 2 pairs per ds_write_b64)
            #pragma unroll
            for (int j = 0; j < 16; j += 2) {
                u64 pk = (u64)(u32)hv[j] | ((u64)(u32)hv[j+1] << 32);
                int elem = sc*32 + 2*j;                     // multiple of 4
                int phys = ((elem & ~7) ^ swz) | (elem & 7);
                *(u64*)&h_lds[sb][phys] = pk;
            }
        }

        // ---- stash x(t+1) into the other x buffer ----
        if (havex) {
            bf16_t (*xn)[EE] = x_lds[(t + 1) & 1];
            *(bf16x8*)&xn[sb][(sc*16    ) ^ swz] = cvt8(xa, xb);
            *(bf16x8*)&xn[sb][(sc*16 + 8) ^ swz] = cvt8(xc, xd);
        }
        __syncthreads();   // B1: h_lds + x stash visible

        // ---- recurrent MFMAs ----
        #pragma unroll
        for (int kt = 0; kt < 16; ++kt) {
            bf16x8 a = *(const bf16x8*)&h_lds[cl][(kt*32 + kgrp*8) ^ ((cl & 7) << 3)];
            acc0 = __builtin_amdgcn_mfma_f32_16x16x32_bf16(a, whf[kt][0], acc0, 0, 0, 0);
            acc1 = __builtin_amdgcn_mfma_f32_16x16x32_bf16(a, whf[kt][1], acc1, 0, 0, 0);
        }

        // ---- preactivations to LDS: D row=(kgrp*4+r)=batch, col=cl ----
        #pragma unroll
        for (int r = 0; r < 4; ++r) {
            P_lds[kgrp*4 + r][wv*32 + cl]      = acc0[r];
            P_lds[kgrp*4 + r][wv*32 + 16 + cl] = acc1[r];
        }
        __syncthreads();   // B2: P visible

        // ---- activations + cell update: thread owns (b,u) and (b+8,u) ----
        {
            int b = tid >> 5, u = tid & 31;
            float4 g0 = *(const float4*)&P_lds[b][u*4];
            float4 g1 = *(const float4*)&P_lds[b + 8][u*4];
            float r0 = sigf(g0.x), f0 = sigf(g0.y), z0 = tanhfast(g0.z), o0 = sigf(g0.w);
            float r1 = sigf(g1.x), f1 = sigf(g1.y), z1 = tanhfast(g1.z), o1 = sigf(g1.w);
            c0 = f0*c0 + r0*z0;
            c1 = f1*c1 + r1*z1;
            float h0 = o0*tanhfast(c0);
            float h1 = o1*tanhfast(c1);
            if (t == TB - 1) {
                out[64 + (size_t)(bg*GB + b    )*HH + ug*32 + u] = h0;
                out[64 + (size_t)(bg*GB + b + 8)*HH + ug*32 + u] = h1;
            }
            // publish tagged pairs: u64 = (t+1)<<32 | h(u+1)<<16 | h(u)
            unsigned s0 = bfbits(h0), s1 = bfbits(h1);
            unsigned n0 = (unsigned)__shfl_down((int)s0, 1);
            unsigned n1 = (unsigned)__shfl_down((int)s1, 1);
            if (!(u & 1)) {
                u64 tg = ((u64)(u32)(t + 1)) << 32;
                u64 v0 = tg | (u64)((s0 & 0xFFFFu) | (n0 << 16));
                u64 v1 = tg | (u64)((s1 & 0xFFFFu) | (n1 << 16));
                size_t base = ((size_t)(t & 1))*NB*NPAIR;
                size_t p0 = base + (size_t)(bg*GB + b    )*NPAIR + ug*16 + (u >> 1);
                size_t p1 = base + (size_t)(bg*GB + b + 8)*NPAIR + ug*16 + (u >> 1);
                __hip_atomic_store(tagH + p0, v0, __ATOMIC_RELAXED, __HIP_MEMORY_SCOPE_AGENT);
                __hip_atomic_store(tagH + p1, v1, __ATOMIC_RELAXED, __HIP_MEMORY_SCOPE_AGENT);
            }
        }
        // no end-of-step barrier, no flag, no fence
    }

    // ---- final FC head: block ug==0 of each group ----
    if (ug == 0) {
        const u64* src = tagH + ((size_t)((TB - 1) & 1))*NB*NPAIR
                              + (size_t)(bg*GB + sb)*NPAIR + sc*16;
        u64 hv[16];
        for (;;) {
            #pragma unroll
            for (int j = 0; j < 16; ++j)
                hv[j] = __hip_atomic_load(src + j, __ATOMIC_RELAXED, __HIP_MEMORY_SCOPE_AGENT);
            bool ok = true;
            #pragma unroll
            for (int j = 0; j < 16; ++j) ok &= ((u32)(hv[j] >> 32) == (u32)TB);
            if (ok) break;
            __builtin_amdgcn_s_sleep(1);
        }
        float s = 0.f;
        #pragma unroll
        for (int j = 0; j < 16; ++j) {
            u32 pl = (u32)hv[j];
            float h0 = __uint_as_float((pl & 0xFFFFu) << 16);
            float h1 = __uint_as_float(pl & 0xFFFF0000u);
            s += h0 * Wfc[sc*32 + 2*j] + h1 * Wfc[sc*32 + 2*j + 1];
        }
        __syncthreads();           // P_lds reuse safe (main loop done)
        P_lds[sb][sc] = s;
        __syncthreads();
        if (tid < 16) {
            float acc = 0.f;
            #pragma unroll
            for (int q = 0; q < 16; ++q) acc += P_lds[tid][q];
            out[bg*GB + tid] = sigf(acc + bfc[0]);
        }
    }
}

extern "C" void kernel_launch(void* const* d_in, const int* in_sizes, int n_in,
                              void* d_out, int out_size, void* d_ws, size_t ws_size,
                              hipStream_t stream) {
    (void)in_sizes; (void)n_in; (void)out_size; (void)ws_size;
    const int*   words = (const int*)d_in[0];
    const float* emb   = (const float*)d_in[1];
    const float* Wi    = (const float*)d_in[2];
    const float* bi    = (const float*)d_in[3];
    const float* Wh    = (const float*)d_in[4];
    const float* bh    = (const float*)d_in[5];
    const float* Wfc   = (const float*)d_in[6];
    const float* bfc   = (const float*)d_in[7];
    float* out = (float*)d_out;

    u64* tagH = (u64*)d_ws;

    // zero tags every launch (tag 0 matches no step; h_{-1} handled by LDS zero)
    hipMemsetAsync(d_ws, 0, (size_t)2*NB*NPAIR*sizeof(u64), stream);

    lstm_persistent<<<dim3(NG*GB), dim3(NT), 0, stream>>>(
        words, emb, Wi, bi, Wh, bh, Wfc, bfc, out, tagH);
}